// Round 9
// baseline (156.752 us; speedup 1.0000x reference)
//
#include <hip/hip_runtime.h>
#include <hip/hip_bf16.h>

constexpr int NN   = 10000;   // nodes
constexpr int INF  = 50;      // in feats
constexpr int HID  = 512;     // hidden
constexpr int OUTF = 121;     // out feats
constexpr int NE   = 160000;  // edges
constexpr int DMAX = 64;      // per-node neighbor capacity (Poisson(16): P(deg>64) ~ 1e-19)

typedef __attribute__((ext_vector_type(8))) short short8;
typedef __attribute__((ext_vector_type(4))) float floatx4;

__device__ inline float bf2f(unsigned short u) {
    union { unsigned int i; float f; } v; v.i = ((unsigned)u) << 16; return v.f;
}
__device__ inline unsigned short f2bf(float f) {
    __hip_bfloat16 h = __float2bfloat16(f);
    return *(unsigned short*)&h;
}

// ---------------- prep: zero cursor + pack weights (MFMA B-frag order) + pack xp ----------------
// B-frag for 16x16x32: lane L holds B[k = kt*32 + (L>>4)*8 + j][n = nt*16 + (L&15)], j=0..7.
// Bp[((nt*KT + kt)*64 + L)*8 + j]: each lane's 8 elems contiguous (16B), wave coalesced.

__global__ __launch_bounds__(256) void k_prep(const float* __restrict__ x,
                                              const float* __restrict__ W1l, const float* __restrict__ W1r,
                                              const float* __restrict__ W2l, const float* __restrict__ W2r,
                                              int* __restrict__ cursor, __hip_bfloat16* __restrict__ xp,
                                              __hip_bfloat16* __restrict__ B1p, __hip_bfloat16* __restrict__ B2p) {
    int idx = blockIdx.x * 256 + threadIdx.x;
    if (idx < NN) cursor[idx] = 0;
    if (idx < 65536) {  // B1p: W1cat[128x512] = vstack(W1l[50], W1r[50], 0[28]); KT=4, NT=32
        int j = idx & 7, L = (idx >> 3) & 63, kt = (idx >> 9) & 3, nt = idx >> 11;
        int k = kt * 32 + ((L >> 4) * 8 + j);
        int n = nt * 16 + (L & 15);
        float v = (k < 50) ? W1l[k * HID + n] : ((k < 100) ? W1r[(k - 50) * HID + n] : 0.f);
        B1p[idx] = __float2bfloat16(v);
    }
    {   // B2p: W2cat[512x256] = [pad128(W2l) | pad128(W2r)]; KT=16, NT=16
        int j = idx & 7, L = (idx >> 3) & 63, kt = (idx >> 9) & 15, nt = idx >> 13;
        int k = kt * 32 + ((L >> 4) * 8 + j);
        int n = nt * 16 + (L & 15);
        float v;
        if (n < 128) v = (n < OUTF) ? W2l[k * OUTF + n] : 0.f;
        else { int c = n - 128; v = (c < OUTF) ? W2r[k * OUTF + c] : 0.f; }
        B2p[idx] = __float2bfloat16(v);
    }
    // xp[NN][64] bf16: one-cache-line gather rows (cols >= 50 zero)
    for (int r = idx; r < NN * 64; r += 131072) {
        int n = r >> 6, c = r & 63;
        xp[r] = __float2bfloat16(c < INF ? x[n * INF + c] : 0.f);
    }
}

// ---------------- fixed-capacity CSR fill ----------------

__global__ __launch_bounds__(256) void k_fill(const int* __restrict__ srcv, const int* __restrict__ dstv,
                                              int* __restrict__ cursor, int* __restrict__ csr) {
    int e = blockIdx.x * 256 + threadIdx.x;
    if (e < NE) {
        int d = dstv[e];
        if ((unsigned)d < (unsigned)NN) {
            int pos = atomicAdd(&cursor[d], 1);
            int s = srcv[e];
            s = min(max(s, 0), NN - 1);               // guard: csr always holds valid node ids
            if (pos < DMAX) csr[d * DMAX + pos] = s;
        }
    }
}

// ---------------- fused agg1 + GEMM1 + GEMM2: persistent 256 blocks x 512 thr (8 waves) ----------------
// Each block loops over row-tiles (16 nodes each), tile = blockIdx.x + k*256.
// Prologue: B2 fragments (phase C weights) cached in registers once per block (2 tiles x 16 ks/wave).
// Phase A: 2 nodes/wave; ids via s_load; gather xp rows (1 cacheline each)
// Phase B: h_tile = relu(As @ W1cat + b1) -> Ht[16][520]; wave w -> cols w*64..+63 (16 MFMA)
// Phase C: waves 0-3 -> Pb (bf16) 32 cols each; waves 4-7 -> Q (fp32); 32 MFMA from cached frags
// __launch_bounds__(512, 2): VGPR cap 256 -> no spills (R7/R8 regression cause: cap 128 vs ~144+ demand)

__global__ __launch_bounds__(512, 2) void k_fused(const __hip_bfloat16* __restrict__ xp,
                                                  const int* __restrict__ cursor, const int* __restrict__ csr,
                                                  const __hip_bfloat16* __restrict__ B1p,
                                                  const float* __restrict__ b1,
                                                  const __hip_bfloat16* __restrict__ B2p,
                                                  __hip_bfloat16* __restrict__ Pb, float* __restrict__ Q) {
    __shared__ __align__(16) unsigned short As[16 * 136];
    __shared__ __align__(16) unsigned short Ht[16 * 520];
    int t = threadIdx.x;
    int w = t >> 6, lane = t & 63, quad = lane >> 4, l16 = lane & 15;
    const unsigned short* xs = (const unsigned short*)xp;

    // ---- prologue: cache phase-C B2 fragments in registers (reused every tile) ----
    int isQ = w >> 2;
    int wh = w & 3;
    int tbase = isQ * 8 + wh * 2;                     // B2p 16-col tile base (R7-proven mapping)
    short8 bf2[2][16];
    {
        const short* Bc0 = (const short*)B2p + ((tbase * 16) * 64 + lane) * 8;
        const short* Bc1 = (const short*)B2p + (((tbase + 1) * 16) * 64 + lane) * 8;
#pragma unroll
        for (int ks = 0; ks < 16; ++ks) {
            bf2[0][ks] = *(const short8*)(Bc0 + ks * 512);
            bf2[1][ks] = *(const short8*)(Bc1 + ks * 512);
        }
    }
    // hoisted bias for phase B epilogue (wave w covers cols w*64..+63)
    float biasv[4];
#pragma unroll
    for (int nt = 0; nt < 4; ++nt) biasv[nt] = b1[w * 64 + nt * 16 + l16];

    for (int tile = blockIdx.x; tile < 625; tile += 256) {
        int m0 = tile * 16;

        // ---- phase A: wave w handles nodes m0 + w*2 + {0,1}; ids via scalar loads ----
#pragma unroll
        for (int p = 0; p < 2; ++p) {
            int nl = w * 2 + p;
            int nu = __builtin_amdgcn_readfirstlane(m0 + nl);   // SGPR node id -> s_load path
            int dt = cursor[nu];
            int d = min(dt, DMAX);
            const int* crow = csr + nu * DMAX;
            float s0 = 0.f, s1 = 0.f, s2 = 0.f, s3 = 0.f;
            int j = 0;
            for (; j + 8 <= d; j += 8) {              // ids arrive as one s_load_dwordx8
                int i0 = crow[j], i1 = crow[j + 1], i2 = crow[j + 2], i3 = crow[j + 3];
                int i4 = crow[j + 4], i5 = crow[j + 5], i6 = crow[j + 6], i7 = crow[j + 7];
                s0 += bf2f(xs[i0 * 64 + lane]);
                s1 += bf2f(xs[i1 * 64 + lane]);
                s2 += bf2f(xs[i2 * 64 + lane]);
                s3 += bf2f(xs[i3 * 64 + lane]);
                s0 += bf2f(xs[i4 * 64 + lane]);
                s1 += bf2f(xs[i5 * 64 + lane]);
                s2 += bf2f(xs[i6 * 64 + lane]);
                s3 += bf2f(xs[i7 * 64 + lane]);
            }
            for (; j < d; ++j) {
                int i0 = crow[j];
                s0 += bf2f(xs[i0 * 64 + lane]);
            }
            float s = (s0 + s1) + (s2 + s3);
            float invd = (dt > 0) ? 1.f / (float)dt : 1.f;
            unsigned short self = xs[nu * 64 + lane];
            if (lane < INF) As[nl * 136 + lane] = f2bf(s * invd);
            As[nl * 136 + 50 + lane] = self;          // cols 50..113 (100..113 zeros from xp pad)
            if (lane < 7) *(unsigned*)&As[nl * 136 + 114 + 2 * lane] = 0u;  // cols 114..127
        }
        __syncthreads();

        // ---- phase B: wave w covers cols w*64 .. +63 (R7-proven mapping) ----
        short8 af[4];
#pragma unroll
        for (int ks = 0; ks < 4; ++ks) af[ks] = *(const short8*)&As[l16 * 136 + ks * 32 + quad * 8];
        {
            floatx4 acc[4];
#pragma unroll
            for (int nt = 0; nt < 4; ++nt) acc[nt] = floatx4{0.f, 0.f, 0.f, 0.f};
#pragma unroll
            for (int nt = 0; nt < 4; ++nt) {
                int ntile = w * 4 + nt;
                const short* Bb = (const short*)B1p + (ntile * 4 * 64 + lane) * 8;
#pragma unroll
                for (int ks = 0; ks < 4; ++ks) {
                    short8 bf = *(const short8*)(Bb + ks * 512);
                    acc[nt] = __builtin_amdgcn_mfma_f32_16x16x32_bf16(af[ks], bf, acc[nt], 0, 0, 0);
                }
            }
#pragma unroll
            for (int nt = 0; nt < 4; ++nt) {
                int col = w * 64 + nt * 16 + l16;
#pragma unroll
                for (int r = 0; r < 4; ++r)
                    Ht[(quad * 4 + r) * 520 + col] = f2bf(fmaxf(acc[nt][r] + biasv[nt], 0.f));
            }
        }
        __syncthreads();

        // ---- phase C: waves 0-3 -> Pb cols wh*32..+31; waves 4-7 -> Q; B2 from registers ----
        {
            floatx4 acc0 = {0.f, 0.f, 0.f, 0.f};
            floatx4 acc1 = {0.f, 0.f, 0.f, 0.f};
#pragma unroll 4
            for (int ks = 0; ks < 16; ++ks) {
                short8 a2 = *(const short8*)&Ht[l16 * 520 + ks * 32 + quad * 8];
                acc0 = __builtin_amdgcn_mfma_f32_16x16x32_bf16(a2, bf2[0][ks], acc0, 0, 0, 0);
                acc1 = __builtin_amdgcn_mfma_f32_16x16x32_bf16(a2, bf2[1][ks], acc1, 0, 0, 0);
            }
            if (!isQ) {
#pragma unroll
                for (int r = 0; r < 4; ++r) {
                    int row = m0 + quad * 4 + r;
                    Pb[row * 128 + wh * 32 + l16]      = __float2bfloat16(acc0[r]);
                    Pb[row * 128 + wh * 32 + 16 + l16] = __float2bfloat16(acc1[r]);
                }
            } else {
#pragma unroll
                for (int r = 0; r < 4; ++r) {
                    int row = m0 + quad * 4 + r;
                    Q[row * 128 + wh * 32 + l16]      = acc0[r];
                    Q[row * 128 + wh * 32 + 16 + l16] = acc1[r];
                }
            }
        }
        __syncthreads();   // As/Ht reuse protection for next tile
    }
}

// ---------------- final: out = mean_agg(Pb)[:, :121] + Q[:, :121] + b2; one wave per node ----------------

__global__ __launch_bounds__(256) void k_final(const __hip_bfloat16* __restrict__ Pb,
                                               const float* __restrict__ Q, const float* __restrict__ b2,
                                               const int* __restrict__ cursor, const int* __restrict__ csr,
                                               float* __restrict__ out) {
    int lane = threadIdx.x & 63;
    int nu = __builtin_amdgcn_readfirstlane(blockIdx.x * 4 + (threadIdx.x >> 6));
    int dt = cursor[nu];
    int d = min(dt, DMAX);
    const int* crow = csr + nu * DMAX;
    const unsigned* Pw = (const unsigned*)Pb;          // 2 bf16 cols per 4B word; lane owns cols 2t, 2t+1
    float lo0 = 0.f, lo1 = 0.f, lo2 = 0.f, lo3 = 0.f;
    float hi0 = 0.f, hi1 = 0.f, hi2 = 0.f, hi3 = 0.f;
    int j = 0;
    for (; j + 8 <= d; j += 8) {                       // ids via one s_load_dwordx8
        int i0 = crow[j], i1 = crow[j + 1], i2 = crow[j + 2], i3 = crow[j + 3];
        int i4 = crow[j + 4], i5 = crow[j + 5], i6 = crow[j + 6], i7 = crow[j + 7];
        unsigned w0 = Pw[i0 * 64 + lane];
        unsigned w1 = Pw[i1 * 64 + lane];
        unsigned w2 = Pw[i2 * 64 + lane];
        unsigned w3 = Pw[i3 * 64 + lane];
        unsigned w4 = Pw[i4 * 64 + lane];
        unsigned w5 = Pw[i5 * 64 + lane];
        unsigned w6 = Pw[i6 * 64 + lane];
        unsigned w7 = Pw[i7 * 64 + lane];
        lo0 += __uint_as_float(w0 << 16); hi0 += __uint_as_float(w0 & 0xffff0000u);
        lo1 += __uint_as_float(w1 << 16); hi1 += __uint_as_float(w1 & 0xffff0000u);
        lo2 += __uint_as_float(w2 << 16); hi2 += __uint_as_float(w2 & 0xffff0000u);
        lo3 += __uint_as_float(w3 << 16); hi3 += __uint_as_float(w3 & 0xffff0000u);
        lo0 += __uint_as_float(w4 << 16); hi0 += __uint_as_float(w4 & 0xffff0000u);
        lo1 += __uint_as_float(w5 << 16); hi1 += __uint_as_float(w5 & 0xffff0000u);
        lo2 += __uint_as_float(w6 << 16); hi2 += __uint_as_float(w6 & 0xffff0000u);
        lo3 += __uint_as_float(w7 << 16); hi3 += __uint_as_float(w7 & 0xffff0000u);
    }
    for (; j < d; ++j) {
        int i0 = crow[j];
        unsigned w0 = Pw[i0 * 64 + lane];
        lo0 += __uint_as_float(w0 << 16); hi0 += __uint_as_float(w0 & 0xffff0000u);
    }
    float slo = (lo0 + lo1) + (lo2 + lo3);
    float shi = (hi0 + hi1) + (hi2 + hi3);
    float invd = (dt > 0) ? 1.f / (float)dt : 1.f;
    int c0 = lane * 2, c1 = lane * 2 + 1;
    if (c0 < OUTF) out[nu * OUTF + c0] = slo * invd + Q[nu * 128 + c0] + b2[c0];
    if (c1 < OUTF) out[nu * OUTF + c1] = shi * invd + Q[nu * 128 + c1] + b2[c1];
}

extern "C" void kernel_launch(void* const* d_in, const int* in_sizes, int n_in,
                              void* d_out, int out_size, void* d_ws, size_t ws_size,
                              hipStream_t stream) {
    const float* x   = (const float*)d_in[0];
    const int* edges = (const int*)d_in[1];
    const float* W1l = (const float*)d_in[2];
    const float* W1r = (const float*)d_in[3];
    const float* b1  = (const float*)d_in[4];
    const float* W2l = (const float*)d_in[5];
    const float* W2r = (const float*)d_in[6];
    const float* b2  = (const float*)d_in[7];
    float* out = (float*)d_out;

    char* ws = (char*)d_ws;
    int* cursor         = (int*)(ws + 0);                    // 40,000 B
    int* csr            = (int*)(ws + 40000);                // 2,560,000 B [NN,64]
    __hip_bfloat16* xp  = (__hip_bfloat16*)(ws + 2600000);   // 1,280,000 B [NN,64]
    __hip_bfloat16* Pb  = (__hip_bfloat16*)(ws + 3880000);   // 2,560,000 B [NN,128]
    float* Q            = (float*)(ws + 6440000);            // 5,120,000 B [NN,128]
    __hip_bfloat16* B1p = (__hip_bfloat16*)(ws + 11560000);  // 131,072 B
    __hip_bfloat16* B2p = (__hip_bfloat16*)(ws + 11691072);  // 262,144 B

    const int* srcv = edges;
    const int* dstv = edges + NE;

    k_prep<<<512, 256, 0, stream>>>(x, W1l, W1r, W2l, W2r, cursor, xp, B1p, B2p);
    k_fill<<<625, 256, 0, stream>>>(srcv, dstv, cursor, csr);
    k_fused<<<256, 512, 0, stream>>>(xp, cursor, csr, B1p, b1, B2p, Pb, Q);
    k_final<<<2500, 256, 0, stream>>>(Pb, Q, b2, cursor, csr, out);
}

// Round 10
// 119.297 us; speedup vs baseline: 1.3140x; 1.3140x over previous
//
#include <hip/hip_runtime.h>
#include <hip/hip_bf16.h>

constexpr int NN   = 10000;   // nodes
constexpr int INF  = 50;      // in feats
constexpr int HID  = 512;     // hidden
constexpr int OUTF = 121;     // out feats
constexpr int NE   = 160000;  // edges
constexpr int DMAX = 64;      // per-node neighbor capacity (Poisson(16): P(deg>64) ~ 1e-19)

typedef __attribute__((ext_vector_type(8))) short short8;
typedef __attribute__((ext_vector_type(4))) float floatx4;

__device__ inline float bf2f(unsigned short u) {
    union { unsigned int i; float f; } v; v.i = ((unsigned)u) << 16; return v.f;
}
__device__ inline unsigned short f2bf(float f) {
    __hip_bfloat16 h = __float2bfloat16(f);
    return *(unsigned short*)&h;
}

// ---------------- prep: zero cursor + pack weights (MFMA B-frag order) + pack xp ----------------
// B-frag for 16x16x32: lane L holds B[k = kt*32 + (L>>4)*8 + j][n = nt*16 + (L&15)], j=0..7.
// Bp[((nt*KT + kt)*64 + L)*8 + j]: each lane's 8 elems contiguous (16B), wave coalesced.

__global__ __launch_bounds__(256) void k_prep(const float* __restrict__ x,
                                              const float* __restrict__ W1l, const float* __restrict__ W1r,
                                              const float* __restrict__ W2l, const float* __restrict__ W2r,
                                              int* __restrict__ cursor, __hip_bfloat16* __restrict__ xp,
                                              __hip_bfloat16* __restrict__ B1p, __hip_bfloat16* __restrict__ B2p) {
    int idx = blockIdx.x * 256 + threadIdx.x;
    if (idx < NN) cursor[idx] = 0;
    if (idx < 65536) {  // B1p: W1cat[128x512] = vstack(W1l[50], W1r[50], 0[28]); KT=4, NT=32
        int j = idx & 7, L = (idx >> 3) & 63, kt = (idx >> 9) & 3, nt = idx >> 11;
        int k = kt * 32 + ((L >> 4) * 8 + j);
        int n = nt * 16 + (L & 15);
        float v = (k < 50) ? W1l[k * HID + n] : ((k < 100) ? W1r[(k - 50) * HID + n] : 0.f);
        B1p[idx] = __float2bfloat16(v);
    }
    {   // B2p: W2cat[512x256] = [pad128(W2l) | pad128(W2r)]; KT=16, NT=16
        int j = idx & 7, L = (idx >> 3) & 63, kt = (idx >> 9) & 15, nt = idx >> 13;
        int k = kt * 32 + ((L >> 4) * 8 + j);
        int n = nt * 16 + (L & 15);
        float v;
        if (n < 128) v = (n < OUTF) ? W2l[k * OUTF + n] : 0.f;
        else { int c = n - 128; v = (c < OUTF) ? W2r[k * OUTF + c] : 0.f; }
        B2p[idx] = __float2bfloat16(v);
    }
    // xp[NN][64] bf16: one-cache-line gather rows (cols >= 50 zero)
    for (int r = idx; r < NN * 64; r += 131072) {
        int n = r >> 6, c = r & 63;
        xp[r] = __float2bfloat16(c < INF ? x[n * INF + c] : 0.f);
    }
}

// ---------------- fixed-capacity CSR fill ----------------

__global__ __launch_bounds__(256) void k_fill(const int* __restrict__ srcv, const int* __restrict__ dstv,
                                              int* __restrict__ cursor, int* __restrict__ csr) {
    int e = blockIdx.x * 256 + threadIdx.x;
    if (e < NE) {
        int d = dstv[e];
        if ((unsigned)d < (unsigned)NN) {
            int pos = atomicAdd(&cursor[d], 1);
            int s = srcv[e];
            s = min(max(s, 0), NN - 1);               // guard: csr always holds valid node ids
            if (pos < DMAX) csr[d * DMAX + pos] = s;
        }
    }
}

// ---------------- layer-1 aggregation: A1 = [mean_agg | self | 0] bf16 [NN,128]; ONE node per wave ----
// High-parallelism gather (10000 independent waves) — the k_final-proven shape.

__global__ __launch_bounds__(256) void k_agg(const __hip_bfloat16* __restrict__ xp,
                                             const int* __restrict__ cursor, const int* __restrict__ csr,
                                             __hip_bfloat16* __restrict__ A1) {
    int lane = threadIdx.x & 63;
    int nu = __builtin_amdgcn_readfirstlane(blockIdx.x * 4 + (threadIdx.x >> 6));
    int dt = cursor[nu];
    int d = min(dt, DMAX);
    const int* crow = csr + nu * DMAX;
    const unsigned short* xs = (const unsigned short*)xp;
    float s0 = 0.f, s1 = 0.f, s2 = 0.f, s3 = 0.f;
    int j = 0;
    for (; j + 8 <= d; j += 8) {                      // ids arrive as one s_load_dwordx8
        int i0 = crow[j], i1 = crow[j + 1], i2 = crow[j + 2], i3 = crow[j + 3];
        int i4 = crow[j + 4], i5 = crow[j + 5], i6 = crow[j + 6], i7 = crow[j + 7];
        s0 += bf2f(xs[i0 * 64 + lane]);
        s1 += bf2f(xs[i1 * 64 + lane]);
        s2 += bf2f(xs[i2 * 64 + lane]);
        s3 += bf2f(xs[i3 * 64 + lane]);
        s0 += bf2f(xs[i4 * 64 + lane]);
        s1 += bf2f(xs[i5 * 64 + lane]);
        s2 += bf2f(xs[i6 * 64 + lane]);
        s3 += bf2f(xs[i7 * 64 + lane]);
    }
    for (; j < d; ++j) {
        int i0 = crow[j];
        s0 += bf2f(xs[i0 * 64 + lane]);
    }
    float s = (s0 + s1) + (s2 + s3);
    float invd = (dt > 0) ? 1.f / (float)dt : 1.f;
    unsigned short self = xs[nu * 64 + lane];
    unsigned short* row = (unsigned short*)A1 + nu * 128;
    if (lane < INF) row[lane] = f2bf(s * invd);       // cols 0..49
    row[50 + lane] = self;                            // cols 50..113 (100..113 zeros from xp pad)
    if (lane < 7) *(unsigned*)&row[114 + 2 * lane] = 0u;  // cols 114..127
}

// ---------------- fused GEMM1+GEMM2: 16 rows per block, 8 waves; h stays in LDS ----------------
// A-frags from global A1 (coalesced 16B/lane); no gather anywhere near the MFMA pipeline.
// Phase B: h = relu(A1 @ W1cat + b1) -> Ht[16][520]; wave w -> cols w*64..+63 (16 MFMA)
// Phase C: waves 0-3 -> Pb (bf16) cols wh*32..+31; waves 4-7 -> Q (fp32); B2p from L2 (NOT reg-cached:
//          R9 measured the compiler spilling such a cache to scratch -> 93MB HBM fetch)

__global__ __launch_bounds__(512, 2) void k_gemm(const __hip_bfloat16* __restrict__ A1,
                                                 const __hip_bfloat16* __restrict__ B1p,
                                                 const float* __restrict__ b1,
                                                 const __hip_bfloat16* __restrict__ B2p,
                                                 __hip_bfloat16* __restrict__ Pb, float* __restrict__ Q) {
    __shared__ __align__(16) unsigned short Ht[16 * 520];
    int t = threadIdx.x;
    int w = t >> 6, lane = t & 63, quad = lane >> 4, l16 = lane & 15;
    int m0 = blockIdx.x * 16;

    // A-fragments straight from global (16B per lane, wave-coalesced within a 16-row slab)
    const short* Arow = (const short*)A1 + (m0 + l16) * 128 + quad * 8;
    short8 af[4];
#pragma unroll
    for (int ks = 0; ks < 4; ++ks) af[ks] = *(const short8*)(Arow + ks * 32);

    // ---- phase B: wave w covers cols w*64 .. +63 (R7-proven mapping) ----
    {
        floatx4 acc[4];
#pragma unroll
        for (int nt = 0; nt < 4; ++nt) acc[nt] = floatx4{0.f, 0.f, 0.f, 0.f};
#pragma unroll
        for (int nt = 0; nt < 4; ++nt) {
            int ntile = w * 4 + nt;
            const short* Bb = (const short*)B1p + (ntile * 4 * 64 + lane) * 8;
#pragma unroll
            for (int ks = 0; ks < 4; ++ks) {
                short8 bf = *(const short8*)(Bb + ks * 512);
                acc[nt] = __builtin_amdgcn_mfma_f32_16x16x32_bf16(af[ks], bf, acc[nt], 0, 0, 0);
            }
        }
#pragma unroll
        for (int nt = 0; nt < 4; ++nt) {
            int col = w * 64 + nt * 16 + l16;
            float bias = b1[col];
#pragma unroll
            for (int r = 0; r < 4; ++r)
                Ht[(quad * 4 + r) * 520 + col] = f2bf(fmaxf(acc[nt][r] + bias, 0.f));
        }
    }
    __syncthreads();

    // ---- phase C: waves 0-3 -> Pb cols wh*32..+31; waves 4-7 -> Q same (R7-proven mapping) ----
    int isQ = w >> 2;
    int wh = w & 3;
    int tbase = isQ * 8 + wh * 2;                     // B2p 16-col tile base
    const short* Bc0 = (const short*)B2p + ((tbase * 16) * 64 + lane) * 8;
    const short* Bc1 = (const short*)B2p + (((tbase + 1) * 16) * 64 + lane) * 8;
    floatx4 acc0 = {0.f, 0.f, 0.f, 0.f};
    floatx4 acc1 = {0.f, 0.f, 0.f, 0.f};
#pragma unroll 4
    for (int ks = 0; ks < 16; ++ks) {
        short8 a2 = *(const short8*)&Ht[l16 * 520 + ks * 32 + quad * 8];
        short8 bf0 = *(const short8*)(Bc0 + ks * 512);
        short8 bf1 = *(const short8*)(Bc1 + ks * 512);
        acc0 = __builtin_amdgcn_mfma_f32_16x16x32_bf16(a2, bf0, acc0, 0, 0, 0);
        acc1 = __builtin_amdgcn_mfma_f32_16x16x32_bf16(a2, bf1, acc1, 0, 0, 0);
    }
    if (!isQ) {
#pragma unroll
        for (int r = 0; r < 4; ++r) {
            int row = m0 + quad * 4 + r;
            Pb[row * 128 + wh * 32 + l16]      = __float2bfloat16(acc0[r]);
            Pb[row * 128 + wh * 32 + 16 + l16] = __float2bfloat16(acc1[r]);
        }
    } else {
#pragma unroll
        for (int r = 0; r < 4; ++r) {
            int row = m0 + quad * 4 + r;
            Q[row * 128 + wh * 32 + l16]      = acc0[r];
            Q[row * 128 + wh * 32 + 16 + l16] = acc1[r];
        }
    }
}

// ---------------- final: out = mean_agg(Pb)[:, :121] + Q[:, :121] + b2; one wave per node ----------------

__global__ __launch_bounds__(256) void k_final(const __hip_bfloat16* __restrict__ Pb,
                                               const float* __restrict__ Q, const float* __restrict__ b2,
                                               const int* __restrict__ cursor, const int* __restrict__ csr,
                                               float* __restrict__ out) {
    int lane = threadIdx.x & 63;
    int nu = __builtin_amdgcn_readfirstlane(blockIdx.x * 4 + (threadIdx.x >> 6));
    int dt = cursor[nu];
    int d = min(dt, DMAX);
    const int* crow = csr + nu * DMAX;
    const unsigned* Pw = (const unsigned*)Pb;          // 2 bf16 cols per 4B word; lane owns cols 2t, 2t+1
    float lo0 = 0.f, lo1 = 0.f, lo2 = 0.f, lo3 = 0.f;
    float hi0 = 0.f, hi1 = 0.f, hi2 = 0.f, hi3 = 0.f;
    int j = 0;
    for (; j + 8 <= d; j += 8) {                       // ids via one s_load_dwordx8
        int i0 = crow[j], i1 = crow[j + 1], i2 = crow[j + 2], i3 = crow[j + 3];
        int i4 = crow[j + 4], i5 = crow[j + 5], i6 = crow[j + 6], i7 = crow[j + 7];
        unsigned w0 = Pw[i0 * 64 + lane];
        unsigned w1 = Pw[i1 * 64 + lane];
        unsigned w2 = Pw[i2 * 64 + lane];
        unsigned w3 = Pw[i3 * 64 + lane];
        unsigned w4 = Pw[i4 * 64 + lane];
        unsigned w5 = Pw[i5 * 64 + lane];
        unsigned w6 = Pw[i6 * 64 + lane];
        unsigned w7 = Pw[i7 * 64 + lane];
        lo0 += __uint_as_float(w0 << 16); hi0 += __uint_as_float(w0 & 0xffff0000u);
        lo1 += __uint_as_float(w1 << 16); hi1 += __uint_as_float(w1 & 0xffff0000u);
        lo2 += __uint_as_float(w2 << 16); hi2 += __uint_as_float(w2 & 0xffff0000u);
        lo3 += __uint_as_float(w3 << 16); hi3 += __uint_as_float(w3 & 0xffff0000u);
        lo0 += __uint_as_float(w4 << 16); hi0 += __uint_as_float(w4 & 0xffff0000u);
        lo1 += __uint_as_float(w5 << 16); hi1 += __uint_as_float(w5 & 0xffff0000u);
        lo2 += __uint_as_float(w6 << 16); hi2 += __uint_as_float(w6 & 0xffff0000u);
        lo3 += __uint_as_float(w7 << 16); hi3 += __uint_as_float(w7 & 0xffff0000u);
    }
    for (; j < d; ++j) {
        int i0 = crow[j];
        unsigned w0 = Pw[i0 * 64 + lane];
        lo0 += __uint_as_float(w0 << 16); hi0 += __uint_as_float(w0 & 0xffff0000u);
    }
    float slo = (lo0 + lo1) + (lo2 + lo3);
    float shi = (hi0 + hi1) + (hi2 + hi3);
    float invd = (dt > 0) ? 1.f / (float)dt : 1.f;
    int c0 = lane * 2, c1 = lane * 2 + 1;
    if (c0 < OUTF) out[nu * OUTF + c0] = slo * invd + Q[nu * 128 + c0] + b2[c0];
    if (c1 < OUTF) out[nu * OUTF + c1] = shi * invd + Q[nu * 128 + c1] + b2[c1];
}

extern "C" void kernel_launch(void* const* d_in, const int* in_sizes, int n_in,
                              void* d_out, int out_size, void* d_ws, size_t ws_size,
                              hipStream_t stream) {
    const float* x   = (const float*)d_in[0];
    const int* edges = (const int*)d_in[1];
    const float* W1l = (const float*)d_in[2];
    const float* W1r = (const float*)d_in[3];
    const float* b1  = (const float*)d_in[4];
    const float* W2l = (const float*)d_in[5];
    const float* W2r = (const float*)d_in[6];
    const float* b2  = (const float*)d_in[7];
    float* out = (float*)d_out;

    char* ws = (char*)d_ws;
    int* cursor         = (int*)(ws + 0);                    // 40,000 B
    int* csr            = (int*)(ws + 40000);                // 2,560,000 B [NN,64]
    __hip_bfloat16* xp  = (__hip_bfloat16*)(ws + 2600000);   // 1,280,000 B [NN,64]
    __hip_bfloat16* Pb  = (__hip_bfloat16*)(ws + 3880000);   // 2,560,000 B [NN,128]
    float* Q            = (float*)(ws + 6440000);            // 5,120,000 B [NN,128]
    __hip_bfloat16* B1p = (__hip_bfloat16*)(ws + 11560000);  // 131,072 B
    __hip_bfloat16* B2p = (__hip_bfloat16*)(ws + 11691072);  // 262,144 B
    __hip_bfloat16* A1  = (__hip_bfloat16*)(ws + 11953216);  // 2,560,000 B [NN,128]

    const int* srcv = edges;
    const int* dstv = edges + NE;

    k_prep<<<512, 256, 0, stream>>>(x, W1l, W1r, W2l, W2r, cursor, xp, B1p, B2p);
    k_fill<<<625, 256, 0, stream>>>(srcv, dstv, cursor, csr);
    k_agg<<<2500, 256, 0, stream>>>(xp, cursor, csr, A1);
    k_gemm<<<625, 512, 0, stream>>>(A1, B1p, b1, B2p, Pb, Q);
    k_final<<<2500, 256, 0, stream>>>(Pb, Q, b2, cursor, csr, out);
}

// Round 11
// 114.045 us; speedup vs baseline: 1.3745x; 1.0460x over previous
//
#include <hip/hip_runtime.h>
#include <hip/hip_bf16.h>

constexpr int NN   = 10000;   // nodes
constexpr int INF  = 50;      // in feats
constexpr int HID  = 512;     // hidden
constexpr int OUTF = 121;     // out feats
constexpr int NE   = 160000;  // edges
constexpr int DMAX = 64;      // per-node neighbor capacity (Poisson(16): P(deg>64) ~ 1e-19)

typedef __attribute__((ext_vector_type(8))) short short8;
typedef __attribute__((ext_vector_type(4))) float floatx4;

__device__ inline float bf2f(unsigned short u) {
    union { unsigned int i; float f; } v; v.i = ((unsigned)u) << 16; return v.f;
}
__device__ inline unsigned short f2bf(float f) {
    __hip_bfloat16 h = __float2bfloat16(f);
    return *(unsigned short*)&h;
}

// ---------------- zero cursor (only true dependency of the CSR fill) ----------------

__global__ __launch_bounds__(256) void k_zero(int* __restrict__ cursor) {
    int i = blockIdx.x * 256 + threadIdx.x;
    if (i < NN) cursor[i] = 0;
}

// ---------------- fill + prep merged: blocks 0..624 fill CSR; blocks 625..1136 pack weights/xp ----
// Prep work is independent of the fill, so it overlaps the fill's atomic latency.
// B-frag for 16x16x32: lane L holds B[k = kt*32 + (L>>4)*8 + j][n = nt*16 + (L&15)], j=0..7.
// Bp[((nt*KT + kt)*64 + L)*8 + j]: each lane's 8 elems contiguous (16B), wave coalesced.

__global__ __launch_bounds__(256) void k_fillprep(const int* __restrict__ srcv, const int* __restrict__ dstv,
                                                  int* __restrict__ cursor, int* __restrict__ csr,
                                                  const float* __restrict__ x,
                                                  const float* __restrict__ W1l, const float* __restrict__ W1r,
                                                  const float* __restrict__ W2l, const float* __restrict__ W2r,
                                                  __hip_bfloat16* __restrict__ xp,
                                                  __hip_bfloat16* __restrict__ B1p, __hip_bfloat16* __restrict__ B2p) {
    int b = blockIdx.x;
    if (b < 625) {
        // ---- CSR fill ----
        int e = b * 256 + threadIdx.x;
        if (e < NE) {
            int d = dstv[e];
            if ((unsigned)d < (unsigned)NN) {
                int pos = atomicAdd(&cursor[d], 1);
                int s = srcv[e];
                s = min(max(s, 0), NN - 1);           // guard: csr always holds valid node ids
                if (pos < DMAX) csr[d * DMAX + pos] = s;
            }
        }
    } else {
        // ---- prep: pack weights + xp ----
        int idx = (b - 625) * 256 + threadIdx.x;      // 0 .. 131071
        if (idx < 65536) {  // B1p: W1cat[128x512] = vstack(W1l[50], W1r[50], 0[28]); KT=4, NT=32
            int j = idx & 7, L = (idx >> 3) & 63, kt = (idx >> 9) & 3, nt = idx >> 11;
            int k = kt * 32 + ((L >> 4) * 8 + j);
            int n = nt * 16 + (L & 15);
            float v = (k < 50) ? W1l[k * HID + n] : ((k < 100) ? W1r[(k - 50) * HID + n] : 0.f);
            B1p[idx] = __float2bfloat16(v);
        }
        {   // B2p: W2cat[512x256] = [pad128(W2l) | pad128(W2r)]; KT=16, NT=16
            int j = idx & 7, L = (idx >> 3) & 63, kt = (idx >> 9) & 15, nt = idx >> 13;
            int k = kt * 32 + ((L >> 4) * 8 + j);
            int n = nt * 16 + (L & 15);
            float v;
            if (n < 128) v = (n < OUTF) ? W2l[k * OUTF + n] : 0.f;
            else { int c = n - 128; v = (c < OUTF) ? W2r[k * OUTF + c] : 0.f; }
            B2p[idx] = __float2bfloat16(v);
        }
        // xp[NN][64] bf16: one-cache-line gather rows (cols >= 50 zero)
        for (int r = idx; r < NN * 64; r += 131072) {
            int n = r >> 6, c = r & 63;
            xp[r] = __float2bfloat16(c < INF ? x[n * INF + c] : 0.f);
        }
    }
}

// ---------------- fused agg1 + GEMM1 + GEMM2: 16 nodes per block, 16 waves (1024 thr) ----------------
// [R8-proven, 114.4us config — byte-identical]
// Phase A: ONE node per wave; ids via s_load_dwordx8; gather xp rows (1 cacheline each)
// Phase B: h_tile = relu(As @ W1cat + b1) -> Ht[16][520]; wave w -> cols w*32..+31 (8 MFMA)
// Phase C: waves 0-7 -> Pb (bf16) 16 cols each; waves 8-15 -> Q (fp32) 16 cols each (16 MFMA)

__global__ __launch_bounds__(1024, 4) void k_fused(const __hip_bfloat16* __restrict__ xp,
                                                   const int* __restrict__ cursor, const int* __restrict__ csr,
                                                   const __hip_bfloat16* __restrict__ B1p,
                                                   const float* __restrict__ b1,
                                                   const __hip_bfloat16* __restrict__ B2p,
                                                   __hip_bfloat16* __restrict__ Pb, float* __restrict__ Q) {
    __shared__ __align__(16) unsigned short As[16 * 136];
    __shared__ __align__(16) unsigned short Ht[16 * 520];
    int t = threadIdx.x;
    int w = t >> 6, lane = t & 63, quad = lane >> 4, l16 = lane & 15;
    int m0 = blockIdx.x * 16;
    const unsigned short* xs = (const unsigned short*)xp;

    // ---- phase A: wave w handles node m0 + w ----
    {
        int nu = __builtin_amdgcn_readfirstlane(m0 + w);   // SGPR node id -> s_load path
        int dt = cursor[nu];
        int d = min(dt, DMAX);
        const int* crow = csr + nu * DMAX;
        float s0 = 0.f, s1 = 0.f, s2 = 0.f, s3 = 0.f;
        int j = 0;
        for (; j + 8 <= d; j += 8) {                  // ids arrive as one s_load_dwordx8
            int i0 = crow[j], i1 = crow[j + 1], i2 = crow[j + 2], i3 = crow[j + 3];
            int i4 = crow[j + 4], i5 = crow[j + 5], i6 = crow[j + 6], i7 = crow[j + 7];
            s0 += bf2f(xs[i0 * 64 + lane]);
            s1 += bf2f(xs[i1 * 64 + lane]);
            s2 += bf2f(xs[i2 * 64 + lane]);
            s3 += bf2f(xs[i3 * 64 + lane]);
            s0 += bf2f(xs[i4 * 64 + lane]);
            s1 += bf2f(xs[i5 * 64 + lane]);
            s2 += bf2f(xs[i6 * 64 + lane]);
            s3 += bf2f(xs[i7 * 64 + lane]);
        }
        for (; j < d; ++j) {
            int i0 = crow[j];
            s0 += bf2f(xs[i0 * 64 + lane]);
        }
        float s = (s0 + s1) + (s2 + s3);
        float invd = (dt > 0) ? 1.f / (float)dt : 1.f;
        unsigned short self = xs[nu * 64 + lane];
        if (lane < INF) As[w * 136 + lane] = f2bf(s * invd);
        As[w * 136 + 50 + lane] = self;               // cols 50..113 (100..113 zeros from xp pad)
        if (lane < 7) *(unsigned*)&As[w * 136 + 114 + 2 * lane] = 0u;  // cols 114..127
    }
    __syncthreads();

    // ---- phase B: wave w covers cols w*32 .. +31 of h ----
    short8 af[4];
#pragma unroll
    for (int ks = 0; ks < 4; ++ks) af[ks] = *(const short8*)&As[l16 * 136 + ks * 32 + quad * 8];
    {
        floatx4 acc[2];
#pragma unroll
        for (int nt = 0; nt < 2; ++nt) acc[nt] = floatx4{0.f, 0.f, 0.f, 0.f};
#pragma unroll
        for (int nt = 0; nt < 2; ++nt) {
            int ntile = w * 2 + nt;
            const short* Bb = (const short*)B1p + (ntile * 4 * 64 + lane) * 8;
#pragma unroll
            for (int ks = 0; ks < 4; ++ks) {
                short8 bf = *(const short8*)(Bb + ks * 512);
                acc[nt] = __builtin_amdgcn_mfma_f32_16x16x32_bf16(af[ks], bf, acc[nt], 0, 0, 0);
            }
        }
#pragma unroll
        for (int nt = 0; nt < 2; ++nt) {
            int col = w * 32 + nt * 16 + l16;
            float bias = b1[col];
#pragma unroll
            for (int r = 0; r < 4; ++r)
                Ht[(quad * 4 + r) * 520 + col] = f2bf(fmaxf(acc[nt][r] + bias, 0.f));
        }
    }
    __syncthreads();

    // ---- phase C: waves 0-7 -> Pb cols wh*16..+15; waves 8-15 -> Q same ----
    int isQ = w >> 3;
    int wh = w & 7;
    int ntile2 = isQ * 8 + wh;                        // B2p 16-col tile index
    floatx4 acc = {0.f, 0.f, 0.f, 0.f};
    const short* Bc = (const short*)B2p + ((ntile2 * 16) * 64 + lane) * 8;
#pragma unroll 4
    for (int ks = 0; ks < 16; ++ks) {
        short8 a2 = *(const short8*)&Ht[l16 * 520 + ks * 32 + quad * 8];
        short8 bf = *(const short8*)(Bc + ks * 512);
        acc = __builtin_amdgcn_mfma_f32_16x16x32_bf16(a2, bf, acc, 0, 0, 0);
    }
    if (!isQ) {
#pragma unroll
        for (int r = 0; r < 4; ++r) {
            int row = m0 + quad * 4 + r;
            Pb[row * 128 + wh * 16 + l16] = __float2bfloat16(acc[r]);
        }
    } else {
#pragma unroll
        for (int r = 0; r < 4; ++r) {
            int row = m0 + quad * 4 + r;
            Q[row * 128 + wh * 16 + l16] = acc[r];
        }
    }
}

// ---------------- final: out = mean_agg(Pb)[:, :121] + Q[:, :121] + b2; one wave per node ----------------

__global__ __launch_bounds__(256) void k_final(const __hip_bfloat16* __restrict__ Pb,
                                               const float* __restrict__ Q, const float* __restrict__ b2,
                                               const int* __restrict__ cursor, const int* __restrict__ csr,
                                               float* __restrict__ out) {
    int lane = threadIdx.x & 63;
    int nu = __builtin_amdgcn_readfirstlane(blockIdx.x * 4 + (threadIdx.x >> 6));
    int dt = cursor[nu];
    int d = min(dt, DMAX);
    const int* crow = csr + nu * DMAX;
    const unsigned* Pw = (const unsigned*)Pb;          // 2 bf16 cols per 4B word; lane owns cols 2t, 2t+1
    float lo0 = 0.f, lo1 = 0.f, lo2 = 0.f, lo3 = 0.f;
    float hi0 = 0.f, hi1 = 0.f, hi2 = 0.f, hi3 = 0.f;
    int j = 0;
    for (; j + 8 <= d; j += 8) {                       // ids via one s_load_dwordx8
        int i0 = crow[j], i1 = crow[j + 1], i2 = crow[j + 2], i3 = crow[j + 3];
        int i4 = crow[j + 4], i5 = crow[j + 5], i6 = crow[j + 6], i7 = crow[j + 7];
        unsigned w0 = Pw[i0 * 64 + lane];
        unsigned w1 = Pw[i1 * 64 + lane];
        unsigned w2 = Pw[i2 * 64 + lane];
        unsigned w3 = Pw[i3 * 64 + lane];
        unsigned w4 = Pw[i4 * 64 + lane];
        unsigned w5 = Pw[i5 * 64 + lane];
        unsigned w6 = Pw[i6 * 64 + lane];
        unsigned w7 = Pw[i7 * 64 + lane];
        lo0 += __uint_as_float(w0 << 16); hi0 += __uint_as_float(w0 & 0xffff0000u);
        lo1 += __uint_as_float(w1 << 16); hi1 += __uint_as_float(w1 & 0xffff0000u);
        lo2 += __uint_as_float(w2 << 16); hi2 += __uint_as_float(w2 & 0xffff0000u);
        lo3 += __uint_as_float(w3 << 16); hi3 += __uint_as_float(w3 & 0xffff0000u);
        lo0 += __uint_as_float(w4 << 16); hi0 += __uint_as_float(w4 & 0xffff0000u);
        lo1 += __uint_as_float(w5 << 16); hi1 += __uint_as_float(w5 & 0xffff0000u);
        lo2 += __uint_as_float(w6 << 16); hi2 += __uint_as_float(w6 & 0xffff0000u);
        lo3 += __uint_as_float(w7 << 16); hi3 += __uint_as_float(w7 & 0xffff0000u);
    }
    for (; j < d; ++j) {
        int i0 = crow[j];
        unsigned w0 = Pw[i0 * 64 + lane];
        lo0 += __uint_as_float(w0 << 16); hi0 += __uint_as_float(w0 & 0xffff0000u);
    }
    float slo = (lo0 + lo1) + (lo2 + lo3);
    float shi = (hi0 + hi1) + (hi2 + hi3);
    float invd = (dt > 0) ? 1.f / (float)dt : 1.f;
    int c0 = lane * 2, c1 = lane * 2 + 1;
    if (c0 < OUTF) out[nu * OUTF + c0] = slo * invd + Q[nu * 128 + c0] + b2[c0];
    if (c1 < OUTF) out[nu * OUTF + c1] = shi * invd + Q[nu * 128 + c1] + b2[c1];
}

extern "C" void kernel_launch(void* const* d_in, const int* in_sizes, int n_in,
                              void* d_out, int out_size, void* d_ws, size_t ws_size,
                              hipStream_t stream) {
    const float* x   = (const float*)d_in[0];
    const int* edges = (const int*)d_in[1];
    const float* W1l = (const float*)d_in[2];
    const float* W1r = (const float*)d_in[3];
    const float* b1  = (const float*)d_in[4];
    const float* W2l = (const float*)d_in[5];
    const float* W2r = (const float*)d_in[6];
    const float* b2  = (const float*)d_in[7];
    float* out = (float*)d_out;

    char* ws = (char*)d_ws;
    int* cursor         = (int*)(ws + 0);                    // 40,000 B
    int* csr            = (int*)(ws + 40000);                // 2,560,000 B [NN,64]
    __hip_bfloat16* xp  = (__hip_bfloat16*)(ws + 2600000);   // 1,280,000 B [NN,64]
    __hip_bfloat16* Pb  = (__hip_bfloat16*)(ws + 3880000);   // 2,560,000 B [NN,128]
    float* Q            = (float*)(ws + 6440000);            // 5,120,000 B [NN,128]
    __hip_bfloat16* B1p = (__hip_bfloat16*)(ws + 11560000);  // 131,072 B
    __hip_bfloat16* B2p = (__hip_bfloat16*)(ws + 11691072);  // 262,144 B

    const int* srcv = edges;
    const int* dstv = edges + NE;

    k_zero<<<40, 256, 0, stream>>>(cursor);
    k_fillprep<<<1137, 256, 0, stream>>>(srcv, dstv, cursor, csr,
                                         x, W1l, W1r, W2l, W2r, xp, B1p, B2p);
    k_fused<<<625, 1024, 0, stream>>>(xp, cursor, csr, B1p, b1, B2p, Pb, Q);
    k_final<<<2500, 256, 0, stream>>>(Pb, Q, b2, cursor, csr, out);
}